// Round 7
// baseline (295.659 us; speedup 1.0000x reference)
//
#include <hip/hip_runtime.h>
#include <hip/hip_bf16.h>

#define DEV_INLINE __device__ __forceinline__

typedef float v2f __attribute__((ext_vector_type(2)));
typedef __fp16 h2v __attribute__((ext_vector_type(2)));   // matches cvt_pkrtz return

DEV_INLINE float rlf(float v, int l) {
    return __uint_as_float(__builtin_amdgcn_readlane(__float_as_uint(v), l));
}
DEV_INLINE int rfl(int v) { return __builtin_amdgcn_readfirstlane(v); }
DEV_INLINE float sigmoid_f(float x) { return __builtin_amdgcn_rcpf(1.0f + __expf(-x)); }

#if __has_builtin(__builtin_amdgcn_fdot2)
DEV_INLINE float fdot2(h2v a, h2v b, float c) { return __builtin_amdgcn_fdot2(a, b, c, false); }
#else
DEV_INLINE float fdot2(h2v a, h2v b, float c) {
    return fmaf((float)a[0], (float)b[0], fmaf((float)a[1], (float)b[1], c));
}
#endif

// LDS-only barrier: lgkmcnt(0) + s_barrier, leaving global prefetches
// (vmcnt) in flight across the barrier (unlike __syncthreads, which drains
// vmcnt(0) and would serialize the embW gather every step). m139/m201 pattern.
DEV_INLINE void lds_barrier() {
    asm volatile("s_waitcnt lgkmcnt(0)" ::: "memory");
    __builtin_amdgcn_s_barrier();
    asm volatile("" ::: "memory");
}

// reduce-add within each 16-lane row via DPP row_ror:N (VALU only)
template<int N>
DEV_INLINE float ror_add(float v) {
    int r = __builtin_amdgcn_update_dpp(0, __float_as_int(v), 0x120 + N, 0xF, 0xF, true);
    return v + __int_as_float(r);
}

// v: low half holds A[j], high half holds B[j] (j = lane&31).
// Returns lo_b = A[j] on all lanes, hi_b = B[j] on all lanes.
DEV_INLINE void bcast_halves(float v, bool low, float& lo_b, float& hi_b) {
#if __has_builtin(__builtin_amdgcn_permlane32_swap)
    auto r = __builtin_amdgcn_permlane32_swap(__float_as_uint(v), __float_as_uint(v),
                                              false, false);
    lo_b = __uint_as_float(r[0]);
    hi_b = __uint_as_float(r[1]);
#else
    float vx = __shfl_xor(v, 32);
    lo_b = low ? v : vx;
    hi_b = low ? vx : v;
#endif
}

// -------- pass 1: embW[v][c] = emb[v,:] @ W1[:,c] + b1[c], W1 staged in LDS --------
__global__ __launch_bounds__(256) void embw_kernel(
    const float* __restrict__ emb, const float* __restrict__ W1,
    const float* __restrict__ b1, float* __restrict__ embW)
{
    __shared__ float w[4096];                 // W1 [32][128], 16 KB
    const int tid = threadIdx.x;
#pragma unroll
    for (int i = 0; i < 16; ++i) w[tid + i * 256] = W1[tid + i * 256];
    __syncthreads();

    const int c   = tid & 127;                // gate column
    const int sub = tid >> 7;                 // 2 vocab rows in flight
    const float bc = b1[c];
    const int v0 = blockIdx.x * 16;

#pragma unroll
    for (int r = sub; r < 16; r += 2) {
        const int v = v0 + r;
        const float* e = emb + (size_t)v * 32;   // wave-uniform -> s_load
        float acc = bc;
#pragma unroll
        for (int d = 0; d < 32; ++d) acc = fmaf(e[d], w[d * 128 + c], acc);
        embW[(size_t)v * 128 + c] = acc;      // natural order: cols 0..127 = i,f,g,o
    }
}

// ---------------- pass 2: recurrent kernel ----------------
// One block (128 thr = 2 waves) = one batch element.
// wave0: gate cols 0..63 (i|f), wave1: cols 64..127 (g|o); 1 col/lane.
// Gates exchanged via LDS float2; h republished as f16 and re-read as
// ds_read_b128 broadcast. Layer 2 (H=1) on wave1: 1 dot2 + 4 DPP row_ror adds.
template<int MODE>
__global__ __launch_bounds__(128, 8) void lstm_kernel(
    const int* __restrict__ x, const float* __restrict__ embW,
    const float* __restrict__ emb, const float* __restrict__ W1,
    const float* __restrict__ b1, const float* __restrict__ U1,
    const float* __restrict__ W2, const float* __restrict__ U2,
    const float* __restrict__ b2, float* __restrict__ out, int T)
{
    const int lane = threadIdx.x & 63;
    const int wv   = threadIdx.x >> 6;        // 0 or 1
    const int b    = blockIdx.x;              // batch element
    const bool low = lane < 32;
    const int col  = wv * 64 + lane;          // my gate column

    // U1 column as f16 k-pairs: 16 VGPRs
    h2v up[16];
#pragma unroll
    for (int m = 0; m < 16; ++m) {
        h2v t;
        t[0] = (__fp16)U1[(2 * m) * 128 + col];
        t[1] = (__fp16)U1[(2 * m + 1) * 128 + col];
        up[m] = t;
    }

    h2v wp[16]; float bcol = 0.f;             // MODE1 fallback only (DCE'd in MODE0)
    if constexpr (MODE == 1) {
#pragma unroll
        for (int m = 0; m < 16; ++m) {
            h2v t;
            t[0] = (__fp16)W1[(2 * m) * 128 + col];
            t[1] = (__fp16)W1[(2 * m + 1) * 128 + col];
            wp[m] = t;
        }
        bcol = b1[col];
    }

    // layer-2 constants: 16-lane group gsel owns gate gsel (order i,f,g,o)
    const int gsel = lane >> 4;
    const int pm   = lane & 15;
    h2v w2s;
    w2s[0] = (__fp16)W2[(2 * pm) * 4 + gsel];
    w2s[1] = (__fp16)W2[(2 * pm + 1) * 4 + gsel];
    const float u2s = U2[gsel];
    const float b2s = b2[gsel];

    __shared__ v2f gbuf[2][32];                     // [wave][j]: {iv,fv} / {gv,ov}
    __shared__ __align__(16) __fp16 hbuf[32];       // h_t as f16

    const int* xrow = x + b * T;

    float h = 0.f, c = 0.f, h2 = 0.f, c2 = 0.f;
    h2v hp[16];                                     // h pairs (uniform across lanes)
#pragma unroll
    for (int m = 0; m < 16; ++m) hp[m] = __builtin_bit_cast(h2v, 0);

    int idxA = rfl(xrow[0]);
    int idxB = rfl(xrow[1]);
    int idxC = rfl(xrow[2]);

    float zc = 0.f, zn = 0.f;
    if constexpr (MODE == 0) {
        zc = embW[(size_t)idxA * 128 + col];        // input part for t=0
        zn = embW[(size_t)idxB * 128 + col];        // t=1
    }

#pragma unroll 2
    for (int t = 0; t < T; ++t) {
        // ---- prefetch input contribution for t+2 (2-step slack > L2/L3 latency;
        //      stays in flight across lds_barrier since vmcnt is not drained) ----
        float zf = 0.f;
        if constexpr (MODE == 0) zf = embW[(size_t)idxC * 128 + col];
        int idxN = rfl(xrow[(t + 3 < T) ? (t + 3) : (T - 1)]);

        // ---- z = input + h_{t-1} @ U1[:,col]  (4 independent dot2 chains) ----
        float a0, a1 = 0.f, a2 = 0.f, a3 = 0.f;
        if constexpr (MODE == 0) {
            a0 = zc;
        } else {
            a0 = bcol;
            const v2f* e2 = reinterpret_cast<const v2f*>(emb + (size_t)idxA * 32);
#pragma unroll
            for (int m = 0; m < 16; m += 2) {
                v2f ea = e2[m], eb = e2[m + 1];
                a0 = fdot2(__builtin_amdgcn_cvt_pkrtz(ea.x, ea.y), wp[m],     a0);
                a1 = fdot2(__builtin_amdgcn_cvt_pkrtz(eb.x, eb.y), wp[m + 1], a1);
            }
        }
#pragma unroll
        for (int m = 0; m < 16; m += 4) {
            a0 = fdot2(hp[m],     up[m],     a0);
            a1 = fdot2(hp[m + 1], up[m + 1], a1);
            a2 = fdot2(hp[m + 2], up[m + 2], a2);
            a3 = fdot2(hp[m + 3], up[m + 3], a3);
        }
        const float z = (a0 + a1) + (a2 + a3);

        // ---- my two gate values, broadcast to both halves, publish to LDS ----
        float iv, fv, gv, ov;
        if (wv == 0) {                       // sig(i) | sig(f)
            float sa = sigmoid_f(z);
            bcast_halves(sa, low, iv, fv);
            if (low) gbuf[0][lane] = (v2f){iv, fv};
        } else {                             // tanh(g) | sig(o)
            float xb = low ? 2.0f * z : z;
            float u  = sigmoid_f(xb);
            float rb = low ? 2.0f * u - 1.0f : u;
            bcast_halves(rb, low, gv, ov);
            if (low) gbuf[1][lane] = (v2f){gv, ov};
        }
        lds_barrier();                       // B1: gates visible (vmcnt untouched)

        {
            v2f other = gbuf[wv ^ 1][lane & 31];
            if (wv == 0) { gv = other.x; ov = other.y; }
            else         { iv = other.x; fv = other.y; }
        }

        // ---- cell/hidden update (identical on all lanes of both waves) ----
        c = fmaf(fv, c, iv * gv);
        float tc = 2.0f * sigmoid_f(2.0f * c) - 1.0f;   // tanh(c)
        h = ov * tc;

        if (wv == 0 && low) hbuf[lane] = (__fp16)h;     // publish h_t
        lds_barrier();                       // B2: h visible

        // ---- reload h pairs for next step (broadcast ds_read_b128 ×4) ----
        {
            const int4* hb4 = reinterpret_cast<const int4*>(hbuf);
            int4 q0 = hb4[0], q1 = hb4[1], q2 = hb4[2], q3 = hb4[3];
            hp[0]  = __builtin_bit_cast(h2v, q0.x); hp[1]  = __builtin_bit_cast(h2v, q0.y);
            hp[2]  = __builtin_bit_cast(h2v, q0.z); hp[3]  = __builtin_bit_cast(h2v, q0.w);
            hp[4]  = __builtin_bit_cast(h2v, q1.x); hp[5]  = __builtin_bit_cast(h2v, q1.y);
            hp[6]  = __builtin_bit_cast(h2v, q1.z); hp[7]  = __builtin_bit_cast(h2v, q1.w);
            hp[8]  = __builtin_bit_cast(h2v, q2.x); hp[9]  = __builtin_bit_cast(h2v, q2.y);
            hp[10] = __builtin_bit_cast(h2v, q2.z); hp[11] = __builtin_bit_cast(h2v, q2.w);
            hp[12] = __builtin_bit_cast(h2v, q3.x); hp[13] = __builtin_bit_cast(h2v, q3.y);
            hp[14] = __builtin_bit_cast(h2v, q3.z); hp[15] = __builtin_bit_cast(h2v, q3.w);
        }

        // ---- layer 2 (H=1) on wave1: z2 = h_t @ W2[:,gsel] + u2s*h2 + b2s ----
        if (wv == 1) {
            const int* hbi = reinterpret_cast<const int*>(hbuf);
            h2v php = __builtin_bit_cast(h2v, hbi[pm]);      // pair pm of h_t
            float p = fdot2(php, w2s, 0.f);
            p = ror_add<8>(p);
            p = ror_add<4>(p);
            p = ror_add<2>(p);
            p = ror_add<1>(p);                               // 16-lane group sum
            float s2 = sigmoid_f(p + fmaf(u2s, h2, b2s));    // all 4 gates at once
            float i2 = rlf(s2, 0),  f2 = rlf(s2, 16);
            float g2 = rlf(s2, 32), o2 = rlf(s2, 48);
            c2 = fmaf(f2, c2, i2 * g2);
            h2 = o2 * sigmoid_f(c2);                         // layer-2 act = sigmoid
        }

        // rotate pipelines
        zc = zn; zn = zf;
        idxA = idxB; idxB = idxC; idxC = idxN;
    }

    if (wv == 1 && lane == 0) out[b] = h2;
}

extern "C" void kernel_launch(void* const* d_in, const int* in_sizes, int n_in,
                              void* d_out, int out_size, void* d_ws, size_t ws_size,
                              hipStream_t stream) {
    const int*   x   = (const int*)d_in[0];
    const float* emb = (const float*)d_in[1];
    const float* W1  = (const float*)d_in[2];
    const float* U1  = (const float*)d_in[3];
    const float* b1  = (const float*)d_in[4];
    const float* W2  = (const float*)d_in[5];
    const float* U2  = (const float*)d_in[6];
    const float* b2  = (const float*)d_in[7];
    float* out = (float*)d_out;

    const int V = in_sizes[1] / 32;       // vocab (30000)
    const int T = 200;
    const int B = in_sizes[0] / T;        // 4096

    const size_t need = (size_t)V * 128 * sizeof(float);   // 15.36 MB
    if (ws_size >= need) {
        float* embW = (float*)d_ws;
        embw_kernel<<<V / 16, 256, 0, stream>>>(emb, W1, b1, embW);
        lstm_kernel<0><<<B, 128, 0, stream>>>(x, embW, emb, W1, b1, U1,
                                              W2, U2, b2, out, T);
    } else {
        lstm_kernel<1><<<B, 128, 0, stream>>>(x, nullptr, emb, W1, b1, U1,
                                              W2, U2, b2, out, T);
    }
}